// Round 4
// baseline (202.803 us; speedup 1.0000x reference)
//
#include <hip/hip_runtime.h>
#include <math.h>

// Problem constants (from reference)
#define BB 8
#define SS 64
#define VV 50257
#define PP 200
#define NMASK 1571                      // ceil(VV/32) dedupe mask words
#define NT 1024                         // threads per block
#define ITER 13                         // ceil(max_nb / NT) float4 iters per thread
constexpr float RP   = 1.2f;
constexpr float TINV = 1.0f / 0.6f;     // 1/temperature

// clang native vector type (required by __builtin_nontemporal_store;
// HIP's float4 is a class and is rejected).
typedef float f32x4 __attribute__((ext_vector_type(4)));

// EXPLICIT TWO-PASS STREAMING. Lesson from r0-r2: the compiler will NOT
// keep 13 float4/thread live across the reduction barriers (observed
// VGPR_Count 44-48 even with a 128-VGPR budget from __launch_bounds__
// (1024,4) -- it spills/restructures, capping at 2.3 TB/s). Meanwhile
// FETCH_SIZE=57MB < 103MB input proves logits are L3-resident, so a
// second read of the row is nearly free. So: stream the row twice.
//
//  p0) zero LDS dedupe mask; threads <200 load prev token and ISSUE the
//      8 scattered batch loads (consumed post-pass-1; loads cannot sink
//      across the barrier, so they stay early and hide under pass 1)
//  p1) stream 13 predicated float4 loads, exp, accumulate (no retention
//      -> ~40 VGPR, no scratch, 2 blocks/CU = 32 waves/CU; one block's
//      stream overlaps the other's reduction bubble)
//  p2) winners fold delta = e^{adj} - e^{raw} into their partial sum
//  p3) block reduce -> li = 1/sum
//  p4) RE-read row (L2/L3-hot; the barrier forces a true reload, no CSE
//      back into retention), exp, scale, non-temporal store
//  p5) barrier orders p4 stores; winners overwrite their masked entry
__global__ __launch_bounds__(NT) void sch_fused_kernel(
        const float* __restrict__ logits,
        const int*   __restrict__ prev,
        float*       __restrict__ out) {
    __shared__ unsigned mask[NMASK];
    __shared__ float ss[16];
    __shared__ float bc_li;

    const int bs  = blockIdx.x;          // bs = b*SS + s
    const int s   = bs & (SS - 1);
    const int tid = threadIdx.x;
    const float* row  = logits + (size_t)bs * VV;
    float*       orow = out    + (size_t)bs * VV;

    // row element offset = bs*VV ; VV % 4 == 1 -> misalignment = bs % 4
    const int a0   = (4 - (bs & 3)) & 3;               // head elems to 16B align
    const int nb   = (VV - a0) >> 2;                   // float4 body count
    const int tail = VV - a0 - (nb << 2);
    const int tstart = a0 + (nb << 2);
    const f32x4* body = (const f32x4*)(row + a0);
    const bool has_head = (tid < a0);
    const bool has_tail = (tid >= 4 && tid < 4 + tail);

    // ---- p0: mask zero + prev load + scattered lv issue ---------------
    int   vtok = -1;
    float lv[BB];
    if (tid < PP) {
        vtok = prev[s * PP + tid];
        #pragma unroll
        for (int b = 0; b < BB; ++b)
            lv[b] = logits[((size_t)(b * SS + s)) * VV + vtok];
    }
    for (int i = tid; i < NMASK; i += NT) mask[i] = 0u;
    __syncthreads();

    bool winner = false;
    if (tid < PP) {
        unsigned bit = 1u << (vtok & 31);
        unsigned old = atomicOr(&mask[vtok >> 5], bit);
        winner = (old & bit) == 0u;      // one winner per distinct token
    }

    // ---- p1: streaming sum pass (no retention) ------------------------
    float accx = 0.f, accy = 0.f, accz = 0.f, accw = 0.f;
    #pragma unroll
    for (int k = 0; k < ITER; ++k) {
        int i = tid + k * NT;
        if (i < nb) {
            f32x4 x = body[i];
            accx += __expf(x.x * TINV);
            accy += __expf(x.y * TINV);
            accz += __expf(x.z * TINV);
            accw += __expf(x.w * TINV);
        }
    }
    float sum = (accx + accy) + (accz + accw);
    if (has_head) sum += __expf(row[tid] * TINV);
    if (has_tail) sum += __expf(row[tstart + tid - 4] * TINV);

    // ---- p2: winner delta (lv loads long since landed) ----------------
    float eadj = 0.0f;
    if (winner) {
        bool all_neg = true;
        #pragma unroll
        for (int b = 0; b < BB; ++b) all_neg = all_neg && (lv[b] < 0.0f);
        const float myraw = lv[bs >> 6];               // this block's b
        const float adj   = all_neg ? myraw * RP : myraw / RP;
        eadj = __expf(adj * TINV);
        sum += eadj - __expf(myraw * TINV);
    }

    // ---- p3: block reduce ---------------------------------------------
    #pragma unroll
    for (int off = 1; off < 64; off <<= 1)
        sum += __shfl_xor(sum, off);
    const int wave = tid >> 6, lane = tid & 63;
    if (lane == 0) ss[wave] = sum;
    __syncthreads();
    if (tid == 0) {
        float S0 = ss[0];
        #pragma unroll
        for (int w = 1; w < 16; ++w) S0 += ss[w];
        bc_li = 1.0f / S0;
    }
    __syncthreads();
    const float li = bc_li;

    // ---- p4: re-read (L2/L3-hot), scale, non-temporal store -----------
    f32x4* obody = (f32x4*)(orow + a0);
    #pragma unroll
    for (int k = 0; k < ITER; ++k) {
        int i = tid + k * NT;
        if (i < nb) {
            f32x4 x = body[i];
            f32x4 o;
            o.x = __expf(x.x * TINV) * li;
            o.y = __expf(x.y * TINV) * li;
            o.z = __expf(x.z * TINV) * li;
            o.w = __expf(x.w * TINV) * li;
            __builtin_nontemporal_store(o, &obody[i]);
        }
    }
    if (has_head)
        __builtin_nontemporal_store(__expf(row[tid] * TINV) * li, &orow[tid]);
    if (has_tail)
        __builtin_nontemporal_store(__expf(row[tstart + tid - 4] * TINV) * li,
                                    &orow[tstart + tid - 4]);

    // ---- p5: winners overwrite masked entries -------------------------
    __syncthreads();   // orders p4 stores before the overwrite
    if (winner) orow[vtok] = eadj * li;
}

extern "C" void kernel_launch(void* const* d_in, const int* in_sizes, int n_in,
                              void* d_out, int out_size, void* d_ws, size_t ws_size,
                              hipStream_t stream) {
    const float* logits = (const float*)d_in[0];
    const int*   prev   = (const int*)d_in[1];
    float* out = (float*)d_out;

    sch_fused_kernel<<<BB * SS, NT, 0, stream>>>(logits, prev, out);
}